// Round 5
// baseline (545.351 us; speedup 1.0000x reference)
//
#include <hip/hip_runtime.h>
#include <math.h>

#define WT_LEN 512
#define N_WT 20
#define B_ 16
#define T_ 262144           // 2^18 per row
#define TOTAL (B_ * T_)     // 4194304
#define CHUNK 8192          // 2^13 elems per block
#define NCHR 32             // chunks per row
#define NCH  512            // total chunks

// inc = (pitch / 44100) * 512 ; f32 division correctly rounded (verified R1/R2).
__device__ __forceinline__ float to_inc1(float x) {
    return (x / 44100.0f) * 512.0f;
}
__device__ __forceinline__ float4 to_inc4(float4 p) {
    float4 r;
    r.x = to_inc1(p.x); r.y = to_inc1(p.y);
    r.z = to_inc1(p.z); r.w = to_inc1(p.w);
    return r;
}

// ---------------------------------------------------------------------------
// U: per-chunk exact adjacent-pair tree reduction -> A13[chunk].
// ---------------------------------------------------------------------------
__global__ __launch_bounds__(1024) void up_kernel(
        const float* __restrict__ pitch, float* __restrict__ A13) {
    __shared__ float red[2048];
    const int t = threadIdx.x;
    const size_t g0 = (size_t)blockIdx.x * CHUNK;

    const float4* p4 = (const float4*)(pitch + g0);
    float4 v0 = to_inc4(p4[2 * t]);
    float4 v1 = to_inc4(p4[2 * t + 1]);
    float t0 = v0.x + v0.y, t1 = v0.z + v0.w;
    float t2 = v1.x + v1.y, t3 = v1.z + v1.w;
    red[t] = (t0 + t1) + (t2 + t3);        // A3[t]
    __syncthreads();
    int off_prev = 0, off = 1024;
    for (int sz = 512; sz >= 1; sz >>= 1) {   // levels 4..13
        if (t < sz) red[off + t] = red[off_prev + 2 * t] + red[off_prev + 2 * t + 1];
        __syncthreads();
        off_prev = off; off += sz;
    }
    if (t == 0) A13[blockIdx.x] = red[2046];
}

// ---------------------------------------------------------------------------
// M: lanes 0..15: exact odd-even scan of each row's 32 chunk totals -> S13 +
// per-row x0. All threads: build tanh'd transposed wavetable WTT once.
// ---------------------------------------------------------------------------
__global__ __launch_bounds__(1024) void mid_kernel(
        const float* __restrict__ A13, const float* __restrict__ pitch,
        const float* __restrict__ wtg, float* __restrict__ S13,
        float* __restrict__ X0, float* __restrict__ WTT) {
    int r = threadIdx.x;
    if (r < B_) {
        float l0[32], l1[16], l2[8], l3[4], l4[2], l5;
        for (int i = 0; i < 32; ++i) l0[i] = A13[r * 32 + i];
        for (int i = 0; i < 16; ++i) l1[i] = l0[2 * i] + l0[2 * i + 1];
        for (int i = 0; i < 8;  ++i) l2[i] = l1[2 * i] + l1[2 * i + 1];
        for (int i = 0; i < 4;  ++i) l3[i] = l2[2 * i] + l2[2 * i + 1];
        for (int i = 0; i < 2;  ++i) l4[i] = l3[2 * i] + l3[2 * i + 1];
        l5 = l4[0] + l4[1];

        float s4[2], s3[4], s2[8], s1[16], s0[32];
        s4[0] = l4[0]; s4[1] = l5;
        s3[0] = l3[0];
        for (int i = 0; i < 2; ++i) {
            s3[2 * i + 1] = s4[i];
            if (2 * i + 2 < 4) s3[2 * i + 2] = s4[i] + l3[2 * i + 2];
        }
        s2[0] = l2[0];
        for (int i = 0; i < 4; ++i) {
            s2[2 * i + 1] = s3[i];
            if (2 * i + 2 < 8) s2[2 * i + 2] = s3[i] + l2[2 * i + 2];
        }
        s1[0] = l1[0];
        for (int i = 0; i < 8; ++i) {
            s1[2 * i + 1] = s2[i];
            if (2 * i + 2 < 16) s1[2 * i + 2] = s2[i] + l1[2 * i + 2];
        }
        s0[0] = l0[0];
        for (int i = 0; i < 16; ++i) {
            s0[2 * i + 1] = s1[i];
            if (2 * i + 2 < 32) s0[2 * i + 2] = s1[i] + l0[2 * i + 2];
        }
        for (int i = 0; i < 32; ++i) S13[r * 32 + i] = s0[i];
        X0[r] = to_inc1(pitch[(size_t)r * T_]);
    }
    for (int e = threadIdx.x; e < WT_LEN * N_WT; e += 1024) {
        int c = e / WT_LEN;
        int i = e - c * WT_LEN;
        float v = wtg[e];
        if (c >= 4) v = tanhf(v);
        WTT[i * N_WT + c] = v;
    }
}

// ---------------------------------------------------------------------------
// DOWNMIX (fused): exact down-sweep rebuild of the odd-even scan (register
// levels 0..3, LDS levels 3..12 — byte-identical math to R4's down_kernel,
// which passed), then the 8 final S values stay in registers and are mixed
// immediately: index -> LDS wavetable gather -> dot(att) -> *amp -> out.
// LDS union: first 8 KB = scan tree, then the same 40 KB buffer is reloaded
// with the wavetable after a barrier. 1024 thr, 40 KB -> 2 blocks/CU (100%).
// ---------------------------------------------------------------------------
__global__ __launch_bounds__(1024) void downmix_kernel(
        const float* __restrict__ pitch, const float* __restrict__ S13,
        const float* __restrict__ X0,    const float* __restrict__ amp,
        const float* __restrict__ att,   const float* __restrict__ WTT,
        float* __restrict__ out) {
    __shared__ float lds[WT_LEN * N_WT];   // 40 KB; lds[0..2046] = scan tree
    const int t = threadIdx.x;
    const int c = blockIdx.x;
    const size_t g0 = (size_t)c * CHUNK;

    // ---- scan: load + divide, register tree levels 0..3 ----
    const float4* p4 = (const float4*)(pitch + g0);
    float4 va = to_inc4(p4[2 * t]);
    float4 vb = to_inc4(p4[2 * t + 1]);
    float x0 = va.x, x2 = va.z, x4 = vb.x, x6 = vb.z;
    float t0 = va.x + va.y, t1 = va.z + va.w;
    float t2 = vb.x + vb.y, t3 = vb.z + vb.w;
    float u0 = t0 + t1, u1 = t2 + t3;
    lds[t] = u0 + u1;               // A3[t]
    __syncthreads();

    // up-sweep levels 4..12
    int bp = 0, b = 1024;
    for (int sz = 512; sz >= 2; sz >>= 1) {
        if (t < sz) lds[b + t] = lds[bp + 2 * t] + lds[bp + 2 * t + 1];
        __syncthreads();
        bp = b; b += sz;
    }

    const float P   = (c & (NCHR - 1)) ? S13[c - 1] : 0.0f;
    const float T13 = S13[c];
    if (t == 0) {
        lds[2044] = P + lds[2044];  // s12[0] = P + A12[0]
        lds[2045] = T13;            // s12[1] = S13[c]
    }
    __syncthreads();

    // down-sweep levels 11..3, in place per slice
    const int offk[10] = {0, 1024, 1536, 1792, 1920, 1984, 2016, 2032, 2040, 2044};
    for (int k = 11; k >= 3; --k) {
        int m = 1 << (13 - k), half = m >> 1;
        int bk = offk[k - 3], bn = offk[k - 2];
        if (t < half) {
            float sn = lds[bn + t];
            int j = 2 * t + 2;
            float av = (j < m) ? lds[bk + j] : 0.0f;
            lds[bk + 2 * t + 1] = sn;
            if (j < m) lds[bk + j] = sn + av;
        }
        if (t == 0) lds[bk] = P + lds[bk];
        __syncthreads();
    }

    // final 8 scan values in registers (same adds as R4's stores)
    float S3prev = t ? lds[t - 1] : P;
    float s3t = lds[t];
    float s[8];
    s[0] = S3prev + x0;
    s[1] = S3prev + t0;
    s[2] = s[1] + x2;
    s[3] = S3prev + u0;
    s[4] = s[3] + x4;
    s[5] = s[3] + t2;
    s[6] = s[5] + x6;
    s[7] = s3t;
    (void)t1; (void)t3; (void)u1;
    __syncthreads();                // all tree reads done -> reuse LDS

    // ---- reload LDS with tanh'd transposed wavetable (40 KB) ----
    {
        const float4* src = (const float4*)WTT;
        float4* dst = (float4*)lds;
        for (int e = t; e < (WT_LEN * N_WT) / 4; e += 1024) dst[e] = src[e];
    }
    __syncthreads();

    // ---- mix the 8 elements owned by this thread ----
    const float x0r = X0[c >> 5];   // row = chunk / NCHR
    const size_t e0 = g0 + (size_t)t * 8;
    float4 am0 = ((const float4*)(amp + e0))[0];
    float4 am1 = ((const float4*)(amp + e0))[1];
    float amv[8] = {am0.x, am0.y, am0.z, am0.w, am1.x, am1.y, am1.z, am1.w};
    float o[8];

#pragma unroll
    for (int j = 0; j < 8; ++j) {
        float y = s[j] - x0r;

        // exact fmod(y, 512)
        float qf  = floorf(y * (1.0f / 512.0f));
        float idx = fmaf(-512.0f, qf, y);
        if (idx < 0.0f)    idx += 512.0f;
        if (idx >= 512.0f) idx -= 512.0f;

        float fl0   = floorf(idx);
        float alpha = idx - fl0;
        int il = ((int)fl0) & (WT_LEN - 1);
        int ih = (il + (alpha > 0.0f ? 1 : 0)) & (WT_LEN - 1);

        const float4* lo4 = (const float4*)(&lds[il * N_WT]);
        const float4* hi4 = (const float4*)(&lds[ih * N_WT]);
        const float4* a4  = (const float4*)(att + (e0 + j) * N_WT);

        float acc = 0.0f;
#pragma unroll
        for (int v = 0; v < 5; ++v) {
            float4 lo = lo4[v];
            float4 hi = hi4[v];
            float4 at = a4[v];
            acc += at.x * (lo.x + alpha * (hi.x - lo.x));
            acc += at.y * (lo.y + alpha * (hi.y - lo.y));
            acc += at.z * (lo.z + alpha * (hi.z - lo.z));
            acc += at.w * (lo.w + alpha * (hi.w - lo.w));
        }
        o[j] = acc * amv[j];
    }

    float4* q4 = (float4*)(out + e0);
    q4[0] = make_float4(o[0], o[1], o[2], o[3]);
    q4[1] = make_float4(o[4], o[5], o[6], o[7]);
}

// ---------------------------------------------------------------------------
extern "C" void kernel_launch(void* const* d_in, const int* in_sizes, int n_in,
                              void* d_out, int out_size, void* d_ws, size_t ws_size,
                              hipStream_t stream) {
    const float* pitch = (const float*)d_in[0];
    const float* amp   = (const float*)d_in[1];
    const float* att   = (const float*)d_in[2];
    const float* wtg   = (const float*)d_in[3];
    float* out = (float*)d_out;

    float* A13 = (float*)d_ws;          // [512]
    float* S13 = A13 + NCH;             // [512]
    float* X0  = S13 + NCH;             // [16]
    float* WTT = X0 + 64;               // [10240] (16-float aligned)

    up_kernel<<<NCH, 1024, 0, stream>>>(pitch, A13);
    mid_kernel<<<1, 1024, 0, stream>>>(A13, pitch, wtg, S13, X0, WTT);
    downmix_kernel<<<NCH, 1024, 0, stream>>>(pitch, S13, X0, amp, att, WTT,
                                             out);
}

// Round 6
// 524.174 us; speedup vs baseline: 1.0404x; 1.0404x over previous
//
#include <hip/hip_runtime.h>
#include <math.h>

#define WT_LEN 512
#define N_WT 20
#define B_ 16
#define T_ 262144           // 2^18 per row
#define TOTAL (B_ * T_)     // 4194304
#define CHUNK 8192          // 2^13 elems per scan block
#define NCHR 32             // chunks per row
#define NCH  512            // total chunks

// inc = (pitch / 44100) * 512 ; f32 division correctly rounded (verified R1/R2).
__device__ __forceinline__ float to_inc1(float x) {
    return (x / 44100.0f) * 512.0f;
}
__device__ __forceinline__ float4 to_inc4(float4 p) {
    float4 r;
    r.x = to_inc1(p.x); r.y = to_inc1(p.y);
    r.z = to_inc1(p.z); r.w = to_inc1(p.w);
    return r;
}

// ---------------------------------------------------------------------------
// U: per-chunk exact adjacent-pair tree reduction -> A13[chunk].  (R4, passed)
// ---------------------------------------------------------------------------
__global__ __launch_bounds__(1024) void up_kernel(
        const float* __restrict__ pitch, float* __restrict__ A13) {
    __shared__ float red[2048];
    const int t = threadIdx.x;
    const size_t g0 = (size_t)blockIdx.x * CHUNK;

    const float4* p4 = (const float4*)(pitch + g0);
    float4 v0 = to_inc4(p4[2 * t]);
    float4 v1 = to_inc4(p4[2 * t + 1]);
    float t0 = v0.x + v0.y, t1 = v0.z + v0.w;
    float t2 = v1.x + v1.y, t3 = v1.z + v1.w;
    red[t] = (t0 + t1) + (t2 + t3);        // A3[t]
    __syncthreads();
    int off_prev = 0, off = 1024;
    for (int sz = 512; sz >= 1; sz >>= 1) {   // levels 4..13
        if (t < sz) red[off + t] = red[off_prev + 2 * t] + red[off_prev + 2 * t + 1];
        __syncthreads();
        off_prev = off; off += sz;
    }
    if (t == 0) A13[blockIdx.x] = red[2046];
}

// ---------------------------------------------------------------------------
// M: lanes 0..15: exact odd-even scan of the 32 chunk totals per row -> S13 +
// per-row x0. All threads: tanh'd transposed wavetable WTT.  (R4, passed)
// ---------------------------------------------------------------------------
__global__ __launch_bounds__(1024) void mid_kernel(
        const float* __restrict__ A13, const float* __restrict__ pitch,
        const float* __restrict__ wtg, float* __restrict__ S13,
        float* __restrict__ X0, float* __restrict__ WTT) {
    int r = threadIdx.x;
    if (r < B_) {
        float l0[32], l1[16], l2[8], l3[4], l4[2], l5;
        for (int i = 0; i < 32; ++i) l0[i] = A13[r * 32 + i];
        for (int i = 0; i < 16; ++i) l1[i] = l0[2 * i] + l0[2 * i + 1];
        for (int i = 0; i < 8;  ++i) l2[i] = l1[2 * i] + l1[2 * i + 1];
        for (int i = 0; i < 4;  ++i) l3[i] = l2[2 * i] + l2[2 * i + 1];
        for (int i = 0; i < 2;  ++i) l4[i] = l3[2 * i] + l3[2 * i + 1];
        l5 = l4[0] + l4[1];

        float s4[2], s3[4], s2[8], s1[16], s0[32];
        s4[0] = l4[0]; s4[1] = l5;
        s3[0] = l3[0];
        for (int i = 0; i < 2; ++i) {
            s3[2 * i + 1] = s4[i];
            if (2 * i + 2 < 4) s3[2 * i + 2] = s4[i] + l3[2 * i + 2];
        }
        s2[0] = l2[0];
        for (int i = 0; i < 4; ++i) {
            s2[2 * i + 1] = s3[i];
            if (2 * i + 2 < 8) s2[2 * i + 2] = s3[i] + l2[2 * i + 2];
        }
        s1[0] = l1[0];
        for (int i = 0; i < 8; ++i) {
            s1[2 * i + 1] = s2[i];
            if (2 * i + 2 < 16) s1[2 * i + 2] = s2[i] + l1[2 * i + 2];
        }
        s0[0] = l0[0];
        for (int i = 0; i < 16; ++i) {
            s0[2 * i + 1] = s1[i];
            if (2 * i + 2 < 32) s0[2 * i + 2] = s1[i] + l0[2 * i + 2];
        }
        for (int i = 0; i < 32; ++i) S13[r * 32 + i] = s0[i];
        X0[r] = to_inc1(pitch[(size_t)r * T_]);
    }
    for (int e = threadIdx.x; e < WT_LEN * N_WT; e += 1024) {
        int c = e / WT_LEN;
        int i = e - c * WT_LEN;
        float v = wtg[e];
        if (c >= 4) v = tanhf(v);
        WTT[i * N_WT + c] = v;
    }
}

// ---------------------------------------------------------------------------
// D: register tree levels 0..3, LDS levels 3..12 (8 KB), write S.  (R4, passed)
// ---------------------------------------------------------------------------
__global__ __launch_bounds__(1024) void down_kernel(
        const float* __restrict__ pitch, const float* __restrict__ S13,
        float* __restrict__ sout) {
    __shared__ float a[2048];
    const int t = threadIdx.x;
    const int c = blockIdx.x;
    const size_t g0 = (size_t)c * CHUNK;

    const float4* p4 = (const float4*)(pitch + g0);
    float4 va = to_inc4(p4[2 * t]);
    float4 vb = to_inc4(p4[2 * t + 1]);
    float x0 = va.x, x2 = va.z, x4 = vb.x, x6 = vb.z;
    float t0 = va.x + va.y, t1 = va.z + va.w;
    float t2 = vb.x + vb.y, t3 = vb.z + vb.w;
    float u0 = t0 + t1, u1 = t2 + t3;
    a[t] = u0 + u1;                 // A3[t]
    __syncthreads();

    int bp = 0, b = 1024;
    for (int sz = 512; sz >= 2; sz >>= 1) {   // up-sweep 4..12
        if (t < sz) a[b + t] = a[bp + 2 * t] + a[bp + 2 * t + 1];
        __syncthreads();
        bp = b; b += sz;
    }

    const float P   = (c & (NCHR - 1)) ? S13[c - 1] : 0.0f;
    const float T13 = S13[c];
    if (t == 0) {
        a[2044] = P + a[2044];      // s12[0] = P + A12[0]
        a[2045] = T13;              // s12[1] = S13[c]
    }
    __syncthreads();

    const int offk[10] = {0, 1024, 1536, 1792, 1920, 1984, 2016, 2032, 2040, 2044};
    for (int k = 11; k >= 3; --k) {           // down-sweep 11..3
        int m = 1 << (13 - k), half = m >> 1;
        int bk = offk[k - 3], bn = offk[k - 2];
        if (t < half) {
            float sn = a[bn + t];
            int j = 2 * t + 2;
            float av = (j < m) ? a[bk + j] : 0.0f;
            a[bk + 2 * t + 1] = sn;
            if (j < m) a[bk + j] = sn + av;
        }
        if (t == 0) a[bk] = P + a[bk];
        __syncthreads();
    }

    float S3prev = t ? a[t - 1] : P;
    float s3t = a[t];
    float s1a = S3prev + t0;
    float s2a = S3prev + u0;
    float s1c = s2a + t2;
    (void)t1; (void)t3; (void)u1;

    float4* q4 = (float4*)(sout + g0);
    q4[2 * t]     = make_float4(S3prev + x0, s1a, s1a + x2, s2a);
    q4[2 * t + 1] = make_float4(s2a + x4, s1c, s1c + x6, s3t);
}

// ---------------------------------------------------------------------------
// mix v3: 2 elements per thread per iteration; ALL global loads for the pair
// issued up front (S float2, amp float2, att 10x float4 = 160 B contiguous
// per thread) -> deep MLP. 2048 blocks x 512 thr x 2 iters covers 4M elems.
// Math per element identical to R4's mix (passed).
// ---------------------------------------------------------------------------
__global__ __launch_bounds__(512) void mix_kernel(
        float* io, const float* __restrict__ X0,
        const float* __restrict__ amp, const float* __restrict__ att,
        const float* __restrict__ WTT) {
    __shared__ float wt_lds[WT_LEN * N_WT];   // [i][c], 40 KB
    {
        const float4* src = (const float4*)WTT;
        float4* dst = (float4*)wt_lds;
#pragma unroll
        for (int r = 0; r < 5; ++r)
            dst[threadIdx.x + 512 * r] = src[threadIdx.x + 512 * r];
    }
    __syncthreads();

    const size_t b0 = (size_t)blockIdx.x * 2048;   // block span: 2048 elems
    const float x0r = X0[b0 >> 18];                // row constant per block

#pragma unroll
    for (int it = 0; it < 2; ++it) {
        const size_t e0 = b0 + (size_t)it * 1024 + (size_t)threadIdx.x * 2;

        // ---- issue all global loads for both elements up front ----
        float2 Sv = *(const float2*)(io + e0);
        float2 am = *(const float2*)(amp + e0);
        const float4* a4 = (const float4*)(att + e0 * N_WT);
        float4 A[10];
#pragma unroll
        for (int v = 0; v < 10; ++v) A[v] = a4[v];

        float res[2];
        float Sj[2] = {Sv.x, Sv.y};
#pragma unroll
        for (int j = 0; j < 2; ++j) {
            float y = Sj[j] - x0r;

            // exact fmod(y, 512)
            float qf  = floorf(y * (1.0f / 512.0f));
            float idx = fmaf(-512.0f, qf, y);
            if (idx < 0.0f)    idx += 512.0f;
            if (idx >= 512.0f) idx -= 512.0f;

            float fl0   = floorf(idx);
            float alpha = idx - fl0;
            int il = ((int)fl0) & (WT_LEN - 1);
            int ih = (il + (alpha > 0.0f ? 1 : 0)) & (WT_LEN - 1);

            const float4* lo4 = (const float4*)(&wt_lds[il * N_WT]);
            const float4* hi4 = (const float4*)(&wt_lds[ih * N_WT]);

            float acc = 0.0f;
#pragma unroll
            for (int v = 0; v < 5; ++v) {
                float4 lo = lo4[v];
                float4 hi = hi4[v];
                float4 at = A[5 * j + v];
                acc += at.x * (lo.x + alpha * (hi.x - lo.x));
                acc += at.y * (lo.y + alpha * (hi.y - lo.y));
                acc += at.z * (lo.z + alpha * (hi.z - lo.z));
                acc += at.w * (lo.w + alpha * (hi.w - lo.w));
            }
            res[j] = acc * (j ? am.y : am.x);
        }
        *(float2*)(io + e0) = make_float2(res[0], res[1]);
    }
}

// ---------------------------------------------------------------------------
extern "C" void kernel_launch(void* const* d_in, const int* in_sizes, int n_in,
                              void* d_out, int out_size, void* d_ws, size_t ws_size,
                              hipStream_t stream) {
    const float* pitch = (const float*)d_in[0];
    const float* amp   = (const float*)d_in[1];
    const float* att   = (const float*)d_in[2];
    const float* wtg   = (const float*)d_in[3];
    float* S = (float*)d_out;           // scan staged in d_out, mixed in place

    float* A13 = (float*)d_ws;          // [512]
    float* S13 = A13 + NCH;             // [512]
    float* X0  = S13 + NCH;             // [16]
    float* WTT = X0 + 64;               // [10240] (16-float aligned)

    up_kernel<<<NCH, 1024, 0, stream>>>(pitch, A13);
    mid_kernel<<<1, 1024, 0, stream>>>(A13, pitch, wtg, S13, X0, WTT);
    down_kernel<<<NCH, 1024, 0, stream>>>(pitch, S13, S);
    mix_kernel<<<2048, 512, 0, stream>>>(S, X0, amp, att, WTT);
}